// Round 18
// baseline (144.993 us; speedup 1.0000x reference)
//
#include <hip/hip_runtime.h>

#define NEARZERO 1e-5f
#define RLEN 15
#define LOG2E 1.4426950408889634f

struct __attribute__((packed, aligned(4))) F3 { float x, y, z; };
static __device__ __forceinline__ F3 ldo(const char* base, unsigned voff) {
    return *reinterpret_cast<const F3*>(base + voff);   // saddr + 32-bit voffset
}

struct Par { float FC, invFC, invLPFC, K1, K2, PERC, UZL, TT, CFMAX, CFRC, CWH, C; };

// prologue-only: snow+soil of t=0
__device__ __forceinline__ void ab_step(
    const F3& f, const F3& d3, const Par& pr,
    float& SP, float& MW, float& SM, float& SLZ,
    float cs, float& rxP, float& k0P)
{
    const float dT   = f.y - pr.TT;
    const float RAIN = (dT >= 0.0f) ? f.x : 0.0f;
    SP += f.x - RAIN;
    const float melt = __builtin_amdgcn_fmed3f(pr.CFMAX * dT, 0.0f, SP);
    MW += melt;  SP -= melt;
    const float refr = __builtin_amdgcn_fmed3f(pr.CFRC * (0.0f - dT), 0.0f, MW);
    SP += refr;  MW -= refr;
    const float tosoil = fmaxf(fmaf(-pr.CWH, SP, MW), 0.0f);
    MW -= tosoil;
    const float sw = fminf(exp2f(fmaf(d3.x, 5.0f, 1.0f) * __log2f(SM * pr.invFC)), 1.0f);
    const float rt = RAIN + tosoil;
    const float rc = rt * sw;
    SM = fmaf(rt, 1.0f - sw, SM);
    const float ex = fmaxf(SM - pr.FC, 0.0f);
    SM = fminf(SM, pr.FC);
    const float ef = fminf(exp2f(fmaf(d3.z, 4.7f, 0.3f) * __log2f(SM * pr.invLPFC)), 1.0f);
    SM = fmaxf(SM - f.z * ef, NEARZERO);
    const float cap = cs * (1.0f - fminf(SM * pr.invFC, 1.0f));
    SM  = fmaxf(SM + cap, NEARZERO);
    SLZ = fmaxf(SLZ - cap, NEARZERO);
    rxP = rc + ex;
    k0P = fmaf(d3.y, 0.85f, 0.05f);
}

// fused: finish(m) [zones+FIR+store] hand-interleaved with ab(m+1) —
// exactly the R13 schedule (97.6 µs verified).
template<int PH>
__device__ __forceinline__ void fused_iter(
    const F3 f, const F3 d3, const Par& pr,
    float& SP, float& MW, float& SM, float& SUZ, float& SLZ,
    float& rxP, float& k0P,
    float (&acc)[RLEN], const float (&w)[RLEN],
    float* outp)
{
    // trans #1: SM(m) ready at entry; latency hidden by snow + upper zone
    const float t1 = __log2f(SM * pr.invFC);
    // snow(m+1)
    const float dT   = f.y - pr.TT;
    const float RAIN = (dT >= 0.0f) ? f.x : 0.0f;
    SP += f.x - RAIN;
    const float melt = __builtin_amdgcn_fmed3f(pr.CFMAX * dT, 0.0f, SP);
    MW += melt;  SP -= melt;
    const float refr = __builtin_amdgcn_fmed3f(pr.CFRC * (0.0f - dT), 0.0f, MW);
    SP += refr;  MW -= refr;
    const float tosoil = fmaxf(fmaf(-pr.CWH, SP, MW), 0.0f);
    MW -= tosoil;
    // finish(m) upper zone
    SUZ += rxP;
    const float PERCv = fminf(SUZ, pr.PERC);
    SUZ -= PERCv;
    const float Q0 = k0P * fmaxf(SUZ - pr.UZL, 0.0f);
    SUZ -= Q0;
    const float Q1 = pr.K1 * SUZ;
    SUZ -= Q1;
    // trans #2; latency hides under lower zone
    const float pBETA = fmaf(d3.x, 5.0f, 1.0f);
    const float sw = fminf(exp2f(pBETA * t1), 1.0f);
    const float rt = RAIN + tosoil;
    // finish(m) lower zone + Qs
    SLZ += PERCv;
    const float Q2 = pr.K2 * SLZ;
    SLZ -= Q2;
    const float Qs = Q0 + Q1 + Q2;
    const float cs = pr.C * SLZ;
    // soil recharge/excess (sw ready)
    const float rc = rt * sw;
    SM = fmaf(rt, 1.0f - sw, SM);
    const float ex = fmaxf(SM - pr.FC, 0.0f);
    SM = fminf(SM, pr.FC);
    const float t2 = __log2f(SM * pr.invLPFC);   // trans #3; hidden by FIR
    // FIR(m) + store (unguarded: OOB lanes returned at kernel entry)
    const float qr = fmaf(w[0], Qs, acc[PH]);
    acc[PH] = 0.0f;
#pragma unroll
    for (int k = 1; k < RLEN; ++k) {
        const int j = (PH + k) % RLEN;           // compile-time
        acc[j] = fmaf(w[k], Qs, acc[j]);
    }
    __builtin_nontemporal_store(qr, outp);
    // trans #4 + soil tail
    const float pBETAET = fmaf(d3.z, 4.7f, 0.3f);
    const float ef = fminf(exp2f(pBETAET * t2), 1.0f);
    SM = fmaxf(SM - f.z * ef, NEARZERO);
    const float cap = cs * (1.0f - fminf(SM * pr.invFC, 1.0f));   // cap <= SLZ (C<=1)
    SM  = fmaxf(SM + cap, NEARZERO);
    SLZ = fmaxf(SLZ - cap, NEARZERO);
    rxP = rc + ex;
    k0P = fmaf(d3.y, 0.85f, 0.05f);
}

// final step's zones+FIR head+store only
template<int PH>
__device__ __forceinline__ void finish_step(
    const Par& pr, float& SUZ, float& SLZ, float rxP, float k0P,
    float (&acc)[RLEN], const float (&w)[RLEN], float* outp)
{
    SUZ += rxP;
    const float PERCv = fminf(SUZ, pr.PERC);
    SUZ -= PERCv;
    const float Q0 = k0P * fmaxf(SUZ - pr.UZL, 0.0f);
    SUZ -= Q0;
    const float Q1 = pr.K1 * SUZ;
    SUZ -= Q1;
    SLZ += PERCv;
    const float Q2 = pr.K2 * SLZ;
    SLZ -= Q2;
    const float Qs = Q0 + Q1 + Q2;
    const float qr = fmaf(w[0], Qs, acc[PH]);
    __builtin_nontemporal_store(qr, outp);
}

__global__ __launch_bounds__(256, 1)
void hbv_kernel(const float* __restrict__ forcing,   // (365,G,3)
                const float* __restrict__ dynr,      // (365,G,3)
                const float* __restrict__ statr,     // (G,15)
                float* __restrict__ out,             // (365,G)
                int G)
{
    const int g = blockIdx.x * 256 + threadIdx.x;
    if (g >= G) return;                // OOB lanes exec-masked for good:
                                       // no per-step guard, no clamps below.

    // ---- static parameters ----
    const float* sp = statr + (size_t)g * 15;
    Par pr;
    pr.FC    = fmaf(sp[0], 950.0f, 50.0f);
    pr.K1    = fmaf(sp[1], 0.49f, 0.01f);
    pr.K2    = fmaf(sp[2], 0.199f, 0.001f);
    const float parLP = fmaf(sp[3], 0.8f, 0.2f);
    pr.PERC  = sp[4] * 10.0f;
    pr.UZL   = sp[5] * 100.0f;
    pr.TT    = fmaf(sp[6], 5.0f, -2.5f);
    pr.CFMAX = fmaf(sp[7], 9.5f, 0.5f);
    pr.CFRC  = (sp[8] * 0.1f) * pr.CFMAX;
    pr.CWH   = sp[9] * 0.2f;
    pr.C     = sp[10];
    const float rout_a = sp[13] * 2.9f;
    const float rout_b = sp[14] * 6.5f;
    pr.invFC   = 1.0f / pr.FC;
    pr.invLPFC = 1.0f / (parLP * pr.FC);

    // ---- routing weights (Gamma(aa)*theta^aa cancels in normalization) ----
    const float aa    = fmaxf(rout_a, 0.0f) + 0.1f;
    const float theta = fmaxf(rout_b, 0.0f) + 0.5f;
    const float am1   = aa - 1.0f;
    const float nitl2 = -LOG2E / theta;
    float w[RLEN];
    float wsum = 0.0f;
#pragma unroll
    for (int k = 0; k < RLEN; ++k) {
        const float tk = (float)k + 0.5f;
        w[k] = exp2f(am1 * __log2f(tk) + tk * nitl2);
        wsum += w[k];
    }
    const float winv = 1.0f / wsum;
#pragma unroll
    for (int k = 0; k < RLEN; ++k) w[k] *= winv;

    // ---- state ----
    float SP_ = 0.001f, MW = 0.001f, SM = 0.001f, SUZ = 0.001f, SLZ = 0.001f;
    float acc[RLEN];
#pragma unroll
    for (int k = 0; k < RLEN; ++k) acc[k] = 0.0f;
    float rxP = 0.0f, k0P = 0.0f;

    // ---- uniform-base + 32-bit running voffsets ----
    const char* fbase = (const char*)forcing;
    const char* dbase = (const char*)dynr;
    char*       obase = (char*)out;
    const unsigned G12 = (unsigned)G * 12u;
    const unsigned G4  = (unsigned)G * 4u;
    unsigned vRun = (unsigned)g * 12u;             // row 0
    unsigned vO   = (unsigned)g * 4u;              // out row 0

    // ---- depth-5 register ring (5 | 15 -> slot = (m+1) % 5, constexpr) ----
    F3 bF[5], bD[5];
#pragma unroll
    for (int r = 0; r < 5; ++r) {
        bF[r] = ldo(fbase, vRun); bD[r] = ldo(dbase, vRun);
        vRun += G12;
    }                                               // vRun now at row 5

    // ---- prologue: ab(0); restage row 5 -> slot 0 ----
    {
        const float cs0 = pr.C * SLZ;
        const F3 f_ = bF[0], d_ = bD[0];
        bF[0] = ldo(fbase, vRun); bD[0] = ldo(dbase, vRun);
        vRun += G12;
        __builtin_amdgcn_sched_barrier(0x7);        // pin VMEM; ALU may cross
        ab_step(f_, d_, pr, SP_, MW, SM, SLZ, cs0, rxP, k0P);
    }

    // Iter m: consume row m+1 (slot (m+1)%5), stage row m+6 into same slot
    // (load->use distance = 5 iterations ~ 2900+ cyc >> HBM latency),
    // run fused_iter<m%15> = finish(m) + ab(m+1).
#define ITER(MM, VOFF) do { \
    constexpr int PH_ = (MM) % RLEN; \
    constexpr int S_  = ((MM) + 1) % 5; \
    const F3 f_ = bF[S_], d_ = bD[S_]; \
    bF[S_] = ldo(fbase, (VOFF)); bD[S_] = ldo(dbase, (VOFF)); \
    __builtin_amdgcn_sched_barrier(0x7); \
    fused_iter<PH_>(f_, d_, pr, SP_, MW, SM, SUZ, SLZ, rxP, k0P, acc, w, \
                    (float*)(obase + vO)); \
    vO += G4; \
} while (0)

#define ITERADV(MM) do { ITER(MM, vRun); vRun += G12; } while (0)

#define ITER_NL(MM) do { \
    constexpr int PH_ = (MM) % RLEN; \
    constexpr int S_  = ((MM) + 1) % 5; \
    const F3 f_ = bF[S_], d_ = bD[S_]; \
    fused_iter<PH_>(f_, d_, pr, SP_, MW, SM, SUZ, SLZ, rxP, k0P, acc, w, \
                    (float*)(obase + vO)); \
    vO += G4; \
} while (0)

    // ---- main: m = 0..344 (23 x 15); stages rows 6..350 ----
    for (int i = 0; i < 23; ++i) {
        ITERADV(0);  ITERADV(1);  ITERADV(2);  ITERADV(3);  ITERADV(4);
        ITERADV(5);  ITERADV(6);  ITERADV(7);  ITERADV(8);  ITERADV(9);
        ITERADV(10); ITERADV(11); ITERADV(12); ITERADV(13); ITERADV(14);
    }
    // ---- penultimate: m = 345..358 stage rows 351..364; m=359 re-stages 364
    //      (its slot, step 365, is never consumed) ----
    ITERADV(0);  ITERADV(1);  ITERADV(2);  ITERADV(3);  ITERADV(4);
    ITERADV(5);  ITERADV(6);  ITERADV(7);  ITERADV(8);  ITERADV(9);
    ITERADV(10); ITERADV(11); ITERADV(12); ITERADV(13);
    ITER(14, (unsigned)g * 12u + 364u * G12);      // m = 359
    // ---- epilogue: m = 360..363 consume rows 361..364 (already staged) ----
    ITER_NL(0); ITER_NL(1); ITER_NL(2); ITER_NL(3);
    // ---- final: finish(364), phase 364 % 15 = 4 ----
    finish_step<4>(pr, SUZ, SLZ, rxP, k0P, acc, w, (float*)(obase + vO));
#undef ITER_NL
#undef ITERADV
#undef ITER
}

extern "C" void kernel_launch(void* const* d_in, const int* in_sizes, int n_in,
                              void* d_out, int out_size, void* d_ws, size_t ws_size,
                              hipStream_t stream) {
    const float* forcing = (const float*)d_in[0];
    const float* dynr    = (const float*)d_in[1];
    const float* statr   = (const float*)d_in[2];
    float* out = (float*)d_out;

    const int G = in_sizes[2] / 15;          // static_raw (G,15); T fixed at 365
    const int block = 256;
    const int grid  = (G + block - 1) / block;
    hbv_kernel<<<grid, block, 0, stream>>>(forcing, dynr, statr, out, G);
}

// Round 19
// 112.420 us; speedup vs baseline: 1.2897x; 1.2897x over previous
//
#include <hip/hip_runtime.h>

#define NEARZERO 1e-5f
#define RLEN 15
#define LOG2E 1.4426950408889634f
#define GRP 10

struct __attribute__((packed, aligned(4))) F3 { float x, y, z; };
static __device__ __forceinline__ F3 ldo(const char* base, unsigned voff) {
    return *reinterpret_cast<const F3*>(base + voff);
}

struct Par { float FC, invFC, invLPFC, K1, K2, PERC, UZL, TT, CFMAX, CFRC, CWH, C; };

struct CState {
    Par pr;
    float SP, MW, SM, SUZ, SLZ, rxP, k0P;
    float acc[RLEN], w[RLEN];
    char* obase;
    unsigned vO, G4;
    bool guard;
};

// snow+soil of t=0 (capillary from initial SLZ)
__device__ __forceinline__ void ab_step0(CState& st, const F3 f, const F3 d3)
{
    const Par& pr = st.pr;
    const float cs = pr.C * st.SLZ;
    const float dT   = f.y - pr.TT;
    const float RAIN = (dT >= 0.0f) ? f.x : 0.0f;
    st.SP += f.x - RAIN;
    const float melt = __builtin_amdgcn_fmed3f(pr.CFMAX * dT, 0.0f, st.SP);
    st.MW += melt;  st.SP -= melt;
    const float refr = __builtin_amdgcn_fmed3f(pr.CFRC * (0.0f - dT), 0.0f, st.MW);
    st.SP += refr;  st.MW -= refr;
    const float tosoil = fmaxf(fmaf(-pr.CWH, st.SP, st.MW), 0.0f);
    st.MW -= tosoil;
    const float sw = fminf(exp2f(fmaf(d3.x, 5.0f, 1.0f) * __log2f(st.SM * pr.invFC)), 1.0f);
    const float rt = RAIN + tosoil;
    const float rc = rt * sw;
    st.SM = fmaf(rt, 1.0f - sw, st.SM);
    const float ex = fmaxf(st.SM - pr.FC, 0.0f);
    st.SM = fminf(st.SM, pr.FC);
    const float ef = fminf(exp2f(fmaf(d3.z, 4.7f, 0.3f) * __log2f(st.SM * pr.invLPFC)), 1.0f);
    st.SM = fmaxf(st.SM - f.z * ef, NEARZERO);
    const float cap = cs * (1.0f - fminf(st.SM * pr.invFC, 1.0f));
    st.SM  = fmaxf(st.SM + cap, NEARZERO);
    st.SLZ = fmaxf(st.SLZ - cap, NEARZERO);
    st.rxP = rc + ex;
    st.k0P = fmaf(d3.y, 0.85f, 0.05f);
}

// R13-verified fused spine: finish(m) [zones+FIR+store] + ab(m+1)
template<int PH>
__device__ __forceinline__ void fused_st(CState& st, const F3 f, const F3 d3)
{
    const Par& pr = st.pr;
    const float t1 = __log2f(st.SM * pr.invFC);          // trans #1
    const float dT   = f.y - pr.TT;
    const float RAIN = (dT >= 0.0f) ? f.x : 0.0f;
    st.SP += f.x - RAIN;
    const float melt = __builtin_amdgcn_fmed3f(pr.CFMAX * dT, 0.0f, st.SP);
    st.MW += melt;  st.SP -= melt;
    const float refr = __builtin_amdgcn_fmed3f(pr.CFRC * (0.0f - dT), 0.0f, st.MW);
    st.SP += refr;  st.MW -= refr;
    const float tosoil = fmaxf(fmaf(-pr.CWH, st.SP, st.MW), 0.0f);
    st.MW -= tosoil;
    st.SUZ += st.rxP;                                    // upper zone of m
    const float PERCv = fminf(st.SUZ, pr.PERC);
    st.SUZ -= PERCv;
    const float Q0 = st.k0P * fmaxf(st.SUZ - pr.UZL, 0.0f);
    st.SUZ -= Q0;
    const float Q1 = pr.K1 * st.SUZ;
    st.SUZ -= Q1;
    const float sw = fminf(exp2f(fmaf(d3.x, 5.0f, 1.0f) * t1), 1.0f);   // trans #2
    const float rt = RAIN + tosoil;
    st.SLZ += PERCv;                                     // lower zone of m
    const float Q2 = pr.K2 * st.SLZ;
    st.SLZ -= Q2;
    const float Qs = Q0 + Q1 + Q2;
    const float cs = pr.C * st.SLZ;
    const float rc = rt * sw;
    st.SM = fmaf(rt, 1.0f - sw, st.SM);
    const float ex = fmaxf(st.SM - pr.FC, 0.0f);
    st.SM = fminf(st.SM, pr.FC);
    const float t2 = __log2f(st.SM * pr.invLPFC);        // trans #3, hidden by FIR
    const float qr = fmaf(st.w[0], Qs, st.acc[PH]);
    st.acc[PH] = 0.0f;
#pragma unroll
    for (int k = 1; k < RLEN; ++k) {
        const int j = (PH + k) % RLEN;                   // compile-time
        st.acc[j] = fmaf(st.w[k], Qs, st.acc[j]);
    }
    if (st.guard) __builtin_nontemporal_store(qr, (float*)(st.obase + st.vO));
    st.vO += st.G4;
    const float ef = fminf(exp2f(fmaf(d3.z, 4.7f, 0.3f) * t2), 1.0f);   // trans #4
    st.SM = fmaxf(st.SM - f.z * ef, NEARZERO);
    const float cap = cs * (1.0f - fminf(st.SM * pr.invFC, 1.0f));
    st.SM  = fmaxf(st.SM + cap, NEARZERO);
    st.SLZ = fmaxf(st.SLZ - cap, NEARZERO);
    st.rxP = rc + ex;
    st.k0P = fmaf(d3.y, 0.85f, 0.05f);
}

template<int PH>
__device__ __forceinline__ void finish_last(CState& st)
{
    const Par& pr = st.pr;
    st.SUZ += st.rxP;
    const float PERCv = fminf(st.SUZ, pr.PERC);
    st.SUZ -= PERCv;
    const float Q0 = st.k0P * fmaxf(st.SUZ - pr.UZL, 0.0f);
    st.SUZ -= Q0;
    const float Q1 = pr.K1 * st.SUZ;
    st.SUZ -= Q1;
    st.SLZ += PERCv;
    const float Q2 = pr.K2 * st.SLZ;
    st.SLZ -= Q2;
    const float Qs = Q0 + Q1 + Q2;
    const float qr = fmaf(st.w[0], Qs, st.acc[PH]);
    if (st.guard) __builtin_nontemporal_store(qr, (float*)(st.obase + st.vO));
}

// ---- consumer group: CNT slots, phases (PH0+I)%15, 1-slot LDS read-ahead ----
template<int PH0, int CNT, bool FIRST, int I>
__device__ __forceinline__ void grp_step(const float (*buf)[64][6], int lane, CState& st,
                                         F3& fA, F3& dA, F3& fB, F3& dB)
{
    if constexpr (I + 1 < CNT) {           // prefetch slot I+1 into set (I+1)&1
        if constexpr (((I + 1) & 1) == 0) {
            fA = *reinterpret_cast<const F3*>(&buf[I + 1][lane][0]);
            dA = *reinterpret_cast<const F3*>(&buf[I + 1][lane][3]);
        } else {
            fB = *reinterpret_cast<const F3*>(&buf[I + 1][lane][0]);
            dB = *reinterpret_cast<const F3*>(&buf[I + 1][lane][3]);
        }
    }
    __builtin_amdgcn_sched_barrier(0x7);   // DS pinned here; VALU may cross
    if constexpr (FIRST && I == 0) {
        ab_step0(st, fA, dA);
    } else {
        constexpr int PH = (PH0 + I) % RLEN;
        if constexpr ((I & 1) == 0) fused_st<PH>(st, fA, dA);
        else                        fused_st<PH>(st, fB, dB);
    }
    if constexpr (I + 1 < CNT)
        grp_step<PH0, CNT, FIRST, I + 1>(buf, lane, st, fA, dA, fB, dB);
}

template<int PH0, int CNT, bool FIRST>
__device__ __forceinline__ void consume_group(const float (*buf)[64][6], int lane, CState& st)
{
    F3 fA, dA, fB, dB;
    fA = *reinterpret_cast<const F3*>(&buf[0][lane][0]);
    dA = *reinterpret_cast<const F3*>(&buf[0][lane][3]);
    fB = fA; dB = dA;                      // overwritten before use
    grp_step<PH0, CNT, FIRST, 0>(buf, lane, st, fA, dA, fB, dB);
}

__global__ __launch_bounds__(128, 1)
void hbv_kernel(const float* __restrict__ forcing,   // (365,G,3)
                const float* __restrict__ dynr,      // (365,G,3)
                const float* __restrict__ statr,     // (G,15)
                float* __restrict__ out,             // (365,G)
                int G)
{
    // 365 rows = groups 0..35 of 10 + group 36 of 5. Group j lives in ring[j&1].
    __shared__ float ring[2][GRP][64][6];            // 30720 B -> 5 blocks/CU by LDS

    const int lane = threadIdx.x & 63;
    const int wave = threadIdx.x >> 6;
    const int g  = blockIdx.x * 64 + lane;
    const int gc = (g < G) ? g : (G - 1);            // clamp loads; stores guarded

    const char* fbase = (const char*)forcing;
    const char* dbase = (const char*)dynr;
    const unsigned G12 = (unsigned)G * 12u;

    if (wave == 0) {
        // ===== producer: stream rows 0..364 into the LDS ring, 10 at a time =====
        unsigned vP = (unsigned)gc * 12u;
        F3 A0[5], B0_[5], A1[5], B1_[5];
#define LOAD5(X, Y) do { _Pragma("unroll") \
        for (int r = 0; r < 5; ++r) { X[r] = ldo(fbase, vP); Y[r] = ldo(dbase, vP); vP += G12; } } while (0)
#define WR5(BP, S0, X, Y) do { _Pragma("unroll") \
        for (int r = 0; r < 5; ++r) { \
            *reinterpret_cast<F3*>(&(BP)[(S0) + r][lane][0]) = X[r]; \
            *reinterpret_cast<F3*>(&(BP)[(S0) + r][lane][3]) = Y[r]; } } while (0)
#define STAGE10(BI) do { float (*bp_)[64][6] = ring[BI]; \
        LOAD5(A0, B0_); LOAD5(A1, B1_); \
        WR5(bp_, 0, A0, B0_); WR5(bp_, 5, A1, B1_); } while (0)

        STAGE10(0);                       // group 0 (rows 0..9)
        __syncthreads();                  // B0
        for (int k = 1; k <= 35; ++k) {   // groups 1..35 (rows 10..359)
            STAGE10(k & 1);
            __syncthreads();              // B1..B35
        }
        {                                 // group 36: rows 360..364 -> ring[0][0..4]
            float (*bp_)[64][6] = ring[0];
            LOAD5(A0, B0_);
            WR5(bp_, 0, A0, B0_);
        }
        __syncthreads();                  // B36
        return;                           // no barriers after this on either path
#undef STAGE10
#undef WR5
#undef LOAD5
    }

    // ===== consumer: R13 fused spine, fed exclusively from LDS =====
    CState st;
    {
        const float* sp = statr + (size_t)gc * 15;
        st.pr.FC    = fmaf(sp[0], 950.0f, 50.0f);
        st.pr.K1    = fmaf(sp[1], 0.49f, 0.01f);
        st.pr.K2    = fmaf(sp[2], 0.199f, 0.001f);
        const float parLP = fmaf(sp[3], 0.8f, 0.2f);
        st.pr.PERC  = sp[4] * 10.0f;
        st.pr.UZL   = sp[5] * 100.0f;
        st.pr.TT    = fmaf(sp[6], 5.0f, -2.5f);
        st.pr.CFMAX = fmaf(sp[7], 9.5f, 0.5f);
        st.pr.CFRC  = (sp[8] * 0.1f) * st.pr.CFMAX;
        st.pr.CWH   = sp[9] * 0.2f;
        st.pr.C     = sp[10];
        const float rout_a = sp[13] * 2.9f;
        const float rout_b = sp[14] * 6.5f;
        st.pr.invFC   = 1.0f / st.pr.FC;
        st.pr.invLPFC = 1.0f / (parLP * st.pr.FC);

        const float aa    = fmaxf(rout_a, 0.0f) + 0.1f;
        const float theta = fmaxf(rout_b, 0.0f) + 0.5f;
        const float am1   = aa - 1.0f;
        const float nitl2 = -LOG2E / theta;
        float wsum = 0.0f;
#pragma unroll
        for (int k = 0; k < RLEN; ++k) {
            const float tk = (float)k + 0.5f;
            st.w[k] = exp2f(am1 * __log2f(tk) + tk * nitl2);
            wsum += st.w[k];
        }
        const float winv = 1.0f / wsum;
#pragma unroll
        for (int k = 0; k < RLEN; ++k) st.w[k] *= winv;

        st.SP = 0.001f; st.MW = 0.001f; st.SM = 0.001f; st.SUZ = 0.001f; st.SLZ = 0.001f;
#pragma unroll
        for (int k = 0; k < RLEN; ++k) st.acc[k] = 0.0f;
        st.rxP = 0.0f; st.k0P = 0.0f;
        st.obase = (char*)out;
        st.vO = (unsigned)g * 4u;
        st.G4 = (unsigned)G * 4u;
        st.guard = (g < G);
    }

    const float (*r0)[64][6] = (const float (*)[64][6])ring[0];
    const float (*r1)[64][6] = (const float (*)[64][6])ring[1];

    __syncthreads();                      // B0: group 0 ready
    consume_group<14, GRP, true>(r0, lane, st);     // rows 0..9 (ab + phases 0..8)
    __syncthreads();                      // B1
    for (int k = 1; k <= 35; ++k) {       // rows 10k..10k+9; PH0 = (10k+14) % 15
        const float (*bp)[64][6] = (k & 1) ? r1 : r0;
        const int f3 = k % 3;
        if (f3 == 1)      consume_group<9,  GRP, false>(bp, lane, st);
        else if (f3 == 2) consume_group<4,  GRP, false>(bp, lane, st);
        else              consume_group<14, GRP, false>(bp, lane, st);
        __syncthreads();                  // B2..B36
    }
    consume_group<14, 5, false>(r0, lane, st);      // rows 360..364 (phases 14,0,1,2,3)
    finish_last<4>(st);                             // stores row 364 (364 % 15 = 4)
}

extern "C" void kernel_launch(void* const* d_in, const int* in_sizes, int n_in,
                              void* d_out, int out_size, void* d_ws, size_t ws_size,
                              hipStream_t stream) {
    const float* forcing = (const float*)d_in[0];
    const float* dynr    = (const float*)d_in[1];
    const float* statr   = (const float*)d_in[2];
    float* out = (float*)d_out;

    const int G = in_sizes[2] / 15;          // static_raw (G,15); T fixed at 365
    const int block = 128;                   // wave 0 = producer, wave 1 = consumer
    const int grid  = (G + 63) / 64;         // 64 cells per block
    hbv_kernel<<<grid, block, 0, stream>>>(forcing, dynr, statr, out, G);
}